// Round 1
// 2202.405 us; speedup vs baseline: 1.8212x; 1.8212x over previous
//
#include <hip/hip_runtime.h>
#include <cstdint>
#include <cstddef>

#define DEV __device__ __forceinline__

constexpr int B_  = 2;
constexpr int J_  = 24;
constexpr int D_  = 32;
constexpr int V_  = 32768;       // 32*32*32
constexpr int JD_ = J_ * D_;     // 768
constexpr int NI_ = 10;
constexpr long long ANN = 50331648LL;  // B*J*D*V elements of each system matrix

typedef __attribute__((ext_vector_type(8))) short bf16x8;   // 8 bf16 (4 VGPRs)
typedef __attribute__((ext_vector_type(4))) float f32x4;

DEV float bflo(unsigned q){ return __uint_as_float(q << 16); }
DEV float bfhi(unsigned q){ return __uint_as_float(q & 0xffff0000u); }
DEV unsigned short f2bf(float f){
  unsigned u = __float_as_uint(f);
  unsigned r = (u + 0x7fffu + ((u >> 16) & 1u)) >> 16;   // RNE
  return (unsigned short)r;
}
DEV float bf2f(unsigned short h){ return __uint_as_float((unsigned)h << 16); }
// fp32 -> bf16 hi + bf16 lo (2-term split; hi+lo carries ~16-17 mantissa bits)
DEV void split2(float v, unsigned short& h, unsigned short& l){
  h = f2bf(v);
  l = f2bf(v - bf2f(h));
}

// ---------------- fp32 -> bf16 convert (8 elems/thread) ----------------
__global__ __launch_bounds__(256) void k_convert(const float* __restrict__ src,
                                                 unsigned short* __restrict__ dst, int n8){
  int t = blockIdx.x * 256 + threadIdx.x;
  if (t >= n8) return;
  const float4* s4 = (const float4*)src;
  float4 a = s4[2*t], b = s4[2*t+1];
  uint4 o;
  o.x = (unsigned)f2bf(a.x) | ((unsigned)f2bf(a.y) << 16);
  o.y = (unsigned)f2bf(a.z) | ((unsigned)f2bf(a.w) << 16);
  o.z = (unsigned)f2bf(b.x) | ((unsigned)f2bf(b.y) << 16);
  o.w = (unsigned)f2bf(b.z) | ((unsigned)f2bf(b.w) << 16);
  ((uint4*)dst)[t] = o;
}

// ---------------- Fortran-order flatten of primal channel 1 ----------------
__global__ __launch_bounds__(256) void k_permute_f(const float* __restrict__ primal,
                                                   float* __restrict__ f){
  const int t = blockIdx.x * 256 + threadIdx.x;       // B*V threads
  const int b = t >> 15, v = t & 32767;
  const int x = v >> 10, y = (v >> 5) & 31, z = v & 31;
  f[t] = primal[((b*5 + 1) << 15) + (z << 10) + (y << 5) + x];
}

// ---------------- evalop1[b,j,d] = sum_v An[b,j,d,v] * f[b,v] ----------------
__global__ __launch_bounds__(256) void k_evalop1_bf(const unsigned short* __restrict__ AnB,
                                                    const float* __restrict__ f_flat,
                                                    float* __restrict__ ev1){
  const int jd = blockIdx.x, b = blockIdx.y;
  const int row = b * JD_ + jd;
  const uint4*  ap = (const uint4*)(AnB + (size_t)row * V_);
  const float4* fp = (const float4*)(f_flat + b * V_);
  float acc = 0.0f;
  for (int i = threadIdx.x; i < V_/8; i += 256){
    uint4 q = ap[i];
    float4 fa = fp[2*i], fb = fp[2*i+1];
    acc += bflo(q.x)*fa.x + bfhi(q.x)*fa.y + bflo(q.y)*fa.z + bfhi(q.y)*fa.w;
    acc += bflo(q.z)*fb.x + bfhi(q.z)*fb.y + bflo(q.w)*fb.z + bfhi(q.w)*fb.w;
  }
  #pragma unroll
  for (int off = 32; off > 0; off >>= 1) acc += __shfl_down(acc, off);
  __shared__ float red[4];
  if ((threadIdx.x & 63) == 0) red[threadIdx.x >> 6] = acc;
  __syncthreads();
  if (threadIdx.x == 0) ev1[row] = red[0] + red[1] + red[2] + red[3];
}

__global__ __launch_bounds__(256) void k_evalop1_f32(const float* __restrict__ An,
                                                     const float* __restrict__ f_flat,
                                                     float* __restrict__ ev1){
  const int jd = blockIdx.x, b = blockIdx.y;
  const int row = b * JD_ + jd;
  const float4* ap = (const float4*)(An + (size_t)row * V_);
  const float4* fp = (const float4*)(f_flat + b * V_);
  float acc = 0.0f;
  for (int i = threadIdx.x; i < V_/4; i += 256){
    float4 av = ap[i], fv = fp[i];
    acc += av.x*fv.x + av.y*fv.y + av.z*fv.z + av.w*fv.w;
  }
  #pragma unroll
  for (int off = 32; off > 0; off >>= 1) acc += __shfl_down(acc, off);
  __shared__ float red[4];
  if ((threadIdx.x & 63) == 0) red[threadIdx.x >> 6] = acc;
  __syncthreads();
  if (threadIdx.x == 0) ev1[row] = red[0] + red[1] + red[2] + red[3];
}

// ---------------- 3x3 conv2d SAME over (J,D) ----------------
template<int CIN, int COUT, bool PRELU, bool ADDTO>
__global__ __launch_bounds__(256) void k_conv2d(const float* __restrict__ in,
                                                const float* __restrict__ ev1,
                                                const float* __restrict__ g,
                                                const float* __restrict__ w,
                                                const float* __restrict__ bias,
                                                const float* __restrict__ alpha,
                                                float* __restrict__ out){
  const int t = blockIdx.x * 256 + threadIdx.x;   // ((b*COUT+o)*J + j)*32 + d
  const int d = t & 31;
  const int j = (t >> 5) % J_;
  const int rest = (t >> 5) / J_;
  const int o = rest % COUT;
  const int b = rest / COUT;
  float acc = bias[o];
  for (int ci = 0; ci < CIN; ci++){
    const float* ip;
    if constexpr (CIN == 7){
      ip = (ci < 5) ? (in + (b*5 + ci)*JD_) : ((ci == 5) ? (ev1 + b*JD_) : (g + b*JD_));
    } else {
      ip = in + (b*CIN + ci)*JD_;
    }
    const float* wp = w + (o*CIN + ci)*9;
    #pragma unroll
    for (int kh = 0; kh < 3; kh++){
      const int jj = j + kh - 1;
      if ((unsigned)jj < (unsigned)J_){
        #pragma unroll
        for (int kw = 0; kw < 3; kw++){
          const int dd = d + kw - 1;
          if ((unsigned)dd < 32u)
            acc += ip[jj*32 + dd] * wp[kh*3 + kw];
        }
      }
    }
  }
  if constexpr (PRELU){
    const float a = alpha[0];
    acc = (acc >= 0.0f) ? acc : a * acc;
  }
  if constexpr (ADDTO) out[t] += acc;
  else                 out[t] = acc;
}

// ---------------- back[b,v] = sum_{j,d} A[b,j,v,d]*dual[b,0,j,d] ----------------
__global__ __launch_bounds__(256) void k_back_bf(const unsigned short* __restrict__ AB,
                                                 const float* __restrict__ dual,
                                                 float* __restrict__ ev2){
  __shared__ float wj[JD_];
  const int b = blockIdx.y;
  for (int i = threadIdx.x; i < JD_; i += 256) wj[i] = dual[b*5*JD_ + i];
  __syncthreads();
  const int lane = threadIdx.x & 63;
  const int wave = threadIdx.x >> 6;
  const int dq = lane & 7;
  const int vi = lane >> 3;
  const int v = blockIdx.x * 32 + wave * 8 + vi;
  float acc = 0.0f;
  for (int j = 0; j < J_; j++){
    const unsigned short* rp = AB + ((size_t)(b*J_ + j) * V_ + v) * 32 + dq*4;
    uint2 q = *(const uint2*)rp;
    const float* wp = &wj[j*32 + dq*4];
    acc += bflo(q.x)*wp[0] + bfhi(q.x)*wp[1] + bflo(q.y)*wp[2] + bfhi(q.y)*wp[3];
  }
  acc += __shfl_xor(acc, 1);
  acc += __shfl_xor(acc, 2);
  acc += __shfl_xor(acc, 4);
  if (dq == 0){
    const int xx = v >> 10, yy = (v >> 5) & 31, zz = v & 31;
    ev2[(b << 15) + (zz << 10) + (yy << 5) + xx] = acc;
  }
}

__global__ __launch_bounds__(256) void k_back_f32(const float* __restrict__ A,
                                                  const float* __restrict__ dual,
                                                  float* __restrict__ ev2){
  __shared__ float wj[JD_];
  const int b = blockIdx.y;
  for (int i = threadIdx.x; i < JD_; i += 256) wj[i] = dual[b*5*JD_ + i];
  __syncthreads();
  const int lane = threadIdx.x & 63;
  const int wave = threadIdx.x >> 6;
  const int dq = lane & 7;
  const int vi = lane >> 3;
  const int v = blockIdx.x * 32 + wave * 8 + vi;
  float acc = 0.0f;
  for (int j = 0; j < J_; j++){
    const float* rp = A + ((size_t)(b*J_ + j) * V_ + v) * 32 + dq*4;
    float4 av = *(const float4*)rp;
    const float* wp = &wj[j*32 + dq*4];
    acc += av.x*wp[0] + av.y*wp[1] + av.z*wp[2] + av.w*wp[3];
  }
  acc += __shfl_xor(acc, 1);
  acc += __shfl_xor(acc, 2);
  acc += __shfl_xor(acc, 4);
  if (dq == 0){
    const int xx = v >> 10, yy = (v >> 5) & 31, zz = v & 31;
    ev2[(b << 15) + (zz << 10) + (yy << 5) + xx] = acc;
  }
}

// ================= MFMA conv3d path =================
// Padded channels-last activation buffers (bf16 hi/lo):
//   L1in : [2b][34 z'][34 y'][36 x'][8ch]   row stride 288
//   H3A/B: [2b][34 z'][34 y'][34 x'][32ch]  row stride 1088
// Interior point (z,y,x) lives at (z+1, y+1, x+1). Borders stay zero (memset once).

// ---- weight fragment prep (runs once; covers all 10 iterations) ----
// frag layout: [k][tap][nt][lane][8e]; B[k8=8*(lane>>4)+e][co=nt*16+(lane&15)]
__global__ __launch_bounds__(256) void k_wprep_l1(const float* __restrict__ pw,
    unsigned short* __restrict__ wfH, unsigned short* __restrict__ wfL){
  const int t = blockIdx.x * 256 + threadIdx.x;
  if (t >= NI_*9*2*64) return;
  const int k = t / 1152, rem = t % 1152;
  const int tap9 = rem >> 7, r2 = rem & 127;
  const int nt = r2 >> 6, lane = r2 & 63;
  const int co = nt*16 + (lane & 15);
  const int kx = lane >> 4;                 // k-group = kx (group 3 dead)
  const size_t ob = (size_t)((k*9 + tap9)*2 + nt)*512 + lane*8;
  #pragma unroll
  for (int e = 0; e < 8; e++){
    const int ci = e;
    float v = 0.0f;
    if (kx < 3 && ci < 6)
      v = pw[(size_t)k*5184 + (size_t)(co*6 + ci)*27 + tap9*3 + kx];
    unsigned short h, l; split2(v, h, l);
    wfH[ob + e] = h; wfL[ob + e] = l;
  }
}

__global__ __launch_bounds__(256) void k_wprep_l2(const float* __restrict__ pw,
    unsigned short* __restrict__ wfH, unsigned short* __restrict__ wfL){
  const int t = blockIdx.x * 256 + threadIdx.x;
  if (t >= NI_*27*2*64) return;
  const int k = t / 3456, rem = t % 3456;
  const int tap = rem >> 7, r2 = rem & 127;
  const int nt = r2 >> 6, lane = r2 & 63;
  const int co = nt*16 + (lane & 15);
  const int cib = (lane >> 4) * 8;
  const size_t ob = (size_t)((k*27 + tap)*2 + nt)*512 + lane*8;
  #pragma unroll
  for (int e = 0; e < 8; e++){
    const float v = pw[(size_t)k*27648 + (size_t)(co*32 + cib + e)*27 + tap];
    unsigned short h, l; split2(v, h, l);
    wfH[ob + e] = h; wfL[ob + e] = l;
  }
}

__global__ __launch_bounds__(256) void k_wprep_l3(const float* __restrict__ pw,
    unsigned short* __restrict__ wfH, unsigned short* __restrict__ wfL){
  const int t = blockIdx.x * 256 + threadIdx.x;
  if (t >= NI_*27*64) return;
  const int k = t / 1728, rem = t % 1728;
  const int tap = rem >> 6, lane = rem & 63;
  const int co = lane & 15;
  const int cib = (lane >> 4) * 8;
  const size_t ob = (size_t)(k*27 + tap)*512 + lane*8;
  #pragma unroll
  for (int e = 0; e < 8; e++){
    float v = 0.0f;
    if (co < 5)
      v = pw[(size_t)k*4320 + (size_t)(co*32 + cib + e)*27 + tap];
    unsigned short h, l; split2(v, h, l);
    wfH[ob + e] = h; wfL[ob + e] = l;
  }
}

// ---- per-iteration: build layer-1 input [primal(5), ev2, 0, 0] hi/lo CL padded ----
__global__ __launch_bounds__(256) void k_prep_l1(const float* __restrict__ primal,
                                                 const float* __restrict__ ev2,
                                                 unsigned short* __restrict__ outH,
                                                 unsigned short* __restrict__ outL){
  const int t = blockIdx.x * 256 + threadIdx.x;  // B*V
  const int b = t >> 15, s = t & 32767;
  const int z = s >> 10, y = (s >> 5) & 31, x = s & 31;
  unsigned H[4], L[4];
  #pragma unroll
  for (int p = 0; p < 4; p++){
    const int c0 = p*2, c1 = p*2 + 1;
    float v0 = (c0 < 5) ? primal[((b*5 + c0) << 15) + s] : ((c0 == 5) ? ev2[(b << 15) + s] : 0.0f);
    float v1 = (c1 < 5) ? primal[((b*5 + c1) << 15) + s] : ((c1 == 5) ? ev2[(b << 15) + s] : 0.0f);
    unsigned short h0, l0, h1, l1;
    split2(v0, h0, l0); split2(v1, h1, l1);
    H[p] = (unsigned)h0 | ((unsigned)h1 << 16);
    L[p] = (unsigned)l0 | ((unsigned)l1 << 16);
  }
  const size_t idx = (size_t)((b*34 + z + 1)*34 + (y + 1))*288 + (size_t)(x + 1)*8;
  *(uint4*)(outH + idx) = make_uint4(H[0], H[1], H[2], H[3]);
  *(uint4*)(outL + idx) = make_uint4(L[0], L[1], L[2], L[3]);
}

// ---- layer 1: 6(->8)ch -> 32ch, kx folded into K (9 taps) ----
// wave = one x-row (b,z,y); 2 mtiles (x halves) x 2 ntiles (co halves)
__global__ __launch_bounds__(256, 2) void k_c3l1(
    const unsigned short* __restrict__ inH, const unsigned short* __restrict__ inL,
    const unsigned short* __restrict__ wfH, const unsigned short* __restrict__ wfL,
    const float* __restrict__ bias, const float* __restrict__ alpha,
    unsigned short* __restrict__ outH, unsigned short* __restrict__ outL)
{
  const int lane = threadIdx.x & 63;
  const int w = blockIdx.x * 4 + (threadIdx.x >> 6);   // 2048 waves
  const int y = w & 31, z = (w >> 5) & 31, b = w >> 10;
  const int lm = lane & 15, lg = lane >> 4;
  const float bv0 = bias[lm], bv1 = bias[16 + lm];
  f32x4 acc[2][2];
  #pragma unroll
  for (int x2 = 0; x2 < 2; x2++){
    acc[x2][0] = {bv0, bv0, bv0, bv0};
    acc[x2][1] = {bv1, bv1, bv1, bv1};
  }
  for (int kz = 0; kz < 3; kz++){
    #pragma unroll
    for (int ky = 0; ky < 3; ky++){
      const int tap = kz*3 + ky;
      const size_t rb = (size_t)((b*34 + z + kz)*34 + (y + ky)) * 288;
      const bf16x8 bh0 = *(const bf16x8*)(wfH + (size_t)(tap*2 + 0)*512 + lane*8);
      const bf16x8 bh1 = *(const bf16x8*)(wfH + (size_t)(tap*2 + 1)*512 + lane*8);
      const bf16x8 bl0 = *(const bf16x8*)(wfL + (size_t)(tap*2 + 0)*512 + lane*8);
      const bf16x8 bl1 = *(const bf16x8*)(wfL + (size_t)(tap*2 + 1)*512 + lane*8);
      #pragma unroll
      for (int x2 = 0; x2 < 2; x2++){
        const size_t off = rb + (size_t)(x2*16 + lm + lg) * 8;   // x' = x + kx(=lg)
        const bf16x8 ah = *(const bf16x8*)(inH + off);
        const bf16x8 al = *(const bf16x8*)(inL + off);
        acc[x2][0] = __builtin_amdgcn_mfma_f32_16x16x32_bf16(ah, bh0, acc[x2][0], 0, 0, 0);
        acc[x2][1] = __builtin_amdgcn_mfma_f32_16x16x32_bf16(ah, bh1, acc[x2][1], 0, 0, 0);
        acc[x2][0] = __builtin_amdgcn_mfma_f32_16x16x32_bf16(al, bh0, acc[x2][0], 0, 0, 0);
        acc[x2][1] = __builtin_amdgcn_mfma_f32_16x16x32_bf16(al, bh1, acc[x2][1], 0, 0, 0);
        acc[x2][0] = __builtin_amdgcn_mfma_f32_16x16x32_bf16(ah, bl0, acc[x2][0], 0, 0, 0);
        acc[x2][1] = __builtin_amdgcn_mfma_f32_16x16x32_bf16(ah, bl1, acc[x2][1], 0, 0, 0);
      }
    }
  }
  const float a0 = alpha[0];
  const size_t ob = (size_t)((b*34 + z + 1)*34 + (y + 1)) * 1088;
  #pragma unroll
  for (int x2 = 0; x2 < 2; x2++){
    #pragma unroll
    for (int nt = 0; nt < 2; nt++){
      const int co = nt*16 + lm;
      #pragma unroll
      for (int r = 0; r < 4; r++){
        float v = acc[x2][nt][r];
        v = (v >= 0.0f) ? v : a0 * v;
        unsigned short h, l; split2(v, h, l);
        const size_t idx = ob + (size_t)(x2*16 + lg*4 + r + 1)*32 + co;
        outH[idx] = h; outL[idx] = l;
      }
    }
  }
}

// ---- layer 2: 32 -> 32 (27 taps, K=cin=32) ----
__global__ __launch_bounds__(256, 2) void k_c3l2(
    const unsigned short* __restrict__ inH, const unsigned short* __restrict__ inL,
    const unsigned short* __restrict__ wfH, const unsigned short* __restrict__ wfL,
    const float* __restrict__ bias, const float* __restrict__ alpha,
    unsigned short* __restrict__ outH, unsigned short* __restrict__ outL)
{
  const int lane = threadIdx.x & 63;
  const int w = blockIdx.x * 4 + (threadIdx.x >> 6);
  const int y = w & 31, z = (w >> 5) & 31, b = w >> 10;
  const int lm = lane & 15, lg = lane >> 4;
  const float bv0 = bias[lm], bv1 = bias[16 + lm];
  f32x4 acc[2][2];
  #pragma unroll
  for (int x2 = 0; x2 < 2; x2++){
    acc[x2][0] = {bv0, bv0, bv0, bv0};
    acc[x2][1] = {bv1, bv1, bv1, bv1};
  }
  for (int kz = 0; kz < 3; kz++){
    for (int ky = 0; ky < 3; ky++){
      const size_t rb = (size_t)((b*34 + z + kz)*34 + (y + ky)) * 1088;
      #pragma unroll
      for (int kx = 0; kx < 3; kx++){
        const int tap = (kz*3 + ky)*3 + kx;
        const bf16x8 bh0 = *(const bf16x8*)(wfH + (size_t)(tap*2 + 0)*512 + lane*8);
        const bf16x8 bh1 = *(const bf16x8*)(wfH + (size_t)(tap*2 + 1)*512 + lane*8);
        const bf16x8 bl0 = *(const bf16x8*)(wfL + (size_t)(tap*2 + 0)*512 + lane*8);
        const bf16x8 bl1 = *(const bf16x8*)(wfL + (size_t)(tap*2 + 1)*512 + lane*8);
        #pragma unroll
        for (int x2 = 0; x2 < 2; x2++){
          const size_t off = rb + (size_t)(x2*16 + lm + kx)*32 + lg*8;
          const bf16x8 ah = *(const bf16x8*)(inH + off);
          const bf16x8 al = *(const bf16x8*)(inL + off);
          acc[x2][0] = __builtin_amdgcn_mfma_f32_16x16x32_bf16(ah, bh0, acc[x2][0], 0, 0, 0);
          acc[x2][1] = __builtin_amdgcn_mfma_f32_16x16x32_bf16(ah, bh1, acc[x2][1], 0, 0, 0);
          acc[x2][0] = __builtin_amdgcn_mfma_f32_16x16x32_bf16(al, bh0, acc[x2][0], 0, 0, 0);
          acc[x2][1] = __builtin_amdgcn_mfma_f32_16x16x32_bf16(al, bh1, acc[x2][1], 0, 0, 0);
          acc[x2][0] = __builtin_amdgcn_mfma_f32_16x16x32_bf16(ah, bl0, acc[x2][0], 0, 0, 0);
          acc[x2][1] = __builtin_amdgcn_mfma_f32_16x16x32_bf16(ah, bl1, acc[x2][1], 0, 0, 0);
        }
      }
    }
  }
  const float a0 = alpha[0];
  const size_t ob = (size_t)((b*34 + z + 1)*34 + (y + 1)) * 1088;
  #pragma unroll
  for (int x2 = 0; x2 < 2; x2++){
    #pragma unroll
    for (int nt = 0; nt < 2; nt++){
      const int co = nt*16 + lm;
      #pragma unroll
      for (int r = 0; r < 4; r++){
        float v = acc[x2][nt][r];
        v = (v >= 0.0f) ? v : a0 * v;
        unsigned short h, l; split2(v, h, l);
        const size_t idx = ob + (size_t)(x2*16 + lg*4 + r + 1)*32 + co;
        outH[idx] = h; outL[idx] = l;
      }
    }
  }
}

// ---- layer 3: 32 -> 5 (co padded to 16; adds into fp32 primal) ----
__global__ __launch_bounds__(256, 2) void k_c3l3(
    const unsigned short* __restrict__ inH, const unsigned short* __restrict__ inL,
    const unsigned short* __restrict__ wfH, const unsigned short* __restrict__ wfL,
    const float* __restrict__ bias,
    float* __restrict__ primal)
{
  const int lane = threadIdx.x & 63;
  const int w = blockIdx.x * 4 + (threadIdx.x >> 6);
  const int y = w & 31, z = (w >> 5) & 31, b = w >> 10;
  const int lm = lane & 15, lg = lane >> 4;
  const float bv = (lm < 5) ? bias[lm] : 0.0f;
  f32x4 acc[2];
  acc[0] = {bv, bv, bv, bv};
  acc[1] = {bv, bv, bv, bv};
  for (int kz = 0; kz < 3; kz++){
    for (int ky = 0; ky < 3; ky++){
      const size_t rb = (size_t)((b*34 + z + kz)*34 + (y + ky)) * 1088;
      #pragma unroll
      for (int kx = 0; kx < 3; kx++){
        const int tap = (kz*3 + ky)*3 + kx;
        const bf16x8 bh = *(const bf16x8*)(wfH + (size_t)tap*512 + lane*8);
        const bf16x8 bl = *(const bf16x8*)(wfL + (size_t)tap*512 + lane*8);
        #pragma unroll
        for (int x2 = 0; x2 < 2; x2++){
          const size_t off = rb + (size_t)(x2*16 + lm + kx)*32 + lg*8;
          const bf16x8 ah = *(const bf16x8*)(inH + off);
          const bf16x8 al = *(const bf16x8*)(inL + off);
          acc[x2] = __builtin_amdgcn_mfma_f32_16x16x32_bf16(ah, bh, acc[x2], 0, 0, 0);
          acc[x2] = __builtin_amdgcn_mfma_f32_16x16x32_bf16(al, bh, acc[x2], 0, 0, 0);
          acc[x2] = __builtin_amdgcn_mfma_f32_16x16x32_bf16(ah, bl, acc[x2], 0, 0, 0);
        }
      }
    }
  }
  if (lm < 5){
    float* pp = primal + ((size_t)(b*5 + lm) << 15) + (z << 10) + (y << 5);
    #pragma unroll
    for (int x2 = 0; x2 < 2; x2++){
      #pragma unroll
      for (int r = 0; r < 4; r++){
        const int x = x2*16 + lg*4 + r;
        pp[x] += acc[x2][r];
      }
    }
  }
}

// ---------------- final output: primal channel 0 ----------------
__global__ __launch_bounds__(256) void k_output(const float* __restrict__ primal,
                                                float* __restrict__ out){
  const int t = blockIdx.x * 256 + threadIdx.x;  // B*V
  const int b = t >> 15, s = t & 32767;
  out[t] = primal[((b*5) << 15) + s];
}

extern "C" void kernel_launch(void* const* d_in, const int* in_sizes, int n_in,
                              void* d_out, int out_size, void* d_ws, size_t ws_size,
                              hipStream_t stream){
  const float* dual_in   = (const float*)d_in[0];
  const float* primal_in = (const float*)d_in[1];
  const float* g    = (const float*)d_in[2];
  const float* An   = (const float*)d_in[3];
  const float* A    = (const float*)d_in[4];
  const float* dw1  = (const float*)d_in[5];
  const float* db1  = (const float*)d_in[6];
  const float* da1  = (const float*)d_in[7];
  const float* dw2  = (const float*)d_in[8];
  const float* db2  = (const float*)d_in[9];
  const float* da2  = (const float*)d_in[10];
  const float* dw3  = (const float*)d_in[11];
  const float* db3  = (const float*)d_in[12];
  const float* pw1  = (const float*)d_in[13];
  const float* pb1  = (const float*)d_in[14];
  const float* pa1  = (const float*)d_in[15];
  const float* pw2  = (const float*)d_in[16];
  const float* pb2  = (const float*)d_in[17];
  const float* pa2  = (const float*)d_in[18];
  const float* pw3  = (const float*)d_in[19];
  const float* pb3  = (const float*)d_in[20];

  // conv3d MFMA buffers (ushort counts)
  constexpr size_t L1_SZ  = 2ull*34*34*36*8;       // 665856
  constexpr size_t H3_SZ  = 2ull*34*34*34*32;      // 2515456
  constexpr size_t WF1_SZ = (size_t)NI_*9*2*512;   // 92160
  constexpr size_t WF2_SZ = (size_t)NI_*27*2*512;  // 276480
  constexpr size_t WF3_SZ = (size_t)NI_*27*512;    // 138240
  constexpr size_t CONV_USH = 2*L1_SZ + 4*H3_SZ + 2*WF1_SZ + 2*WF2_SZ + 2*WF3_SZ;
  constexpr size_t F_FLOATS = 7680 + 327680 + 65536 + 1536 + 49152 + 49152 + 65536;

  const size_t bf_bytes = (size_t)ANN * 2u * 2u;   // two bf16 system matrices
  const bool use_bf16 = ws_size >= bf_bytes + CONV_USH*2 + F_FLOATS*4;

  unsigned short* AnB = (unsigned short*)d_ws;
  unsigned short* AB  = AnB + ANN;
  unsigned short* u0 = use_bf16 ? (AB + ANN) : (unsigned short*)d_ws;
  unsigned short* L1H  = u0;
  unsigned short* L1L  = L1H + L1_SZ;
  unsigned short* H3AH = L1L + L1_SZ;
  unsigned short* H3AL = H3AH + H3_SZ;
  unsigned short* H3BH = H3AL + H3_SZ;
  unsigned short* H3BL = H3BH + H3_SZ;
  unsigned short* WF1H = H3BL + H3_SZ;
  unsigned short* WF1L = WF1H + WF1_SZ;
  unsigned short* WF2H = WF1L + WF1_SZ;
  unsigned short* WF2L = WF2H + WF2_SZ;
  unsigned short* WF3H = WF2L + WF2_SZ;
  unsigned short* WF3L = WF3H + WF3_SZ;

  float* base = (float*)(WF3L + WF3_SZ);
  float* dual   = base;             // 7680
  float* primal = dual + 7680;      // 327680
  float* f_flat = primal + 327680;  // 65536
  float* ev1    = f_flat + 65536;   // 1536
  float* h2a    = ev1 + 1536;       // 49152
  float* h2b    = h2a + 49152;      // 49152
  float* ev2    = h2b + 49152;      // 65536 (stored [B,Z,Y,X])

  hipMemcpyAsync(dual, dual_in, 7680 * sizeof(float), hipMemcpyDeviceToDevice, stream);
  hipMemcpyAsync(primal, primal_in, 327680 * sizeof(float), hipMemcpyDeviceToDevice, stream);

  if (use_bf16){
    const int n8 = (int)(ANN / 8);
    k_convert<<<n8 / 256, 256, 0, stream>>>(An, AnB, n8);
    k_convert<<<n8 / 256, 256, 0, stream>>>(A,  AB,  n8);
  }

  // zero padded activation buffers once (borders stay zero; interiors rewritten each iter)
  hipMemsetAsync(L1H, 0, (2*L1_SZ + 4*H3_SZ) * sizeof(unsigned short), stream);

  // weight fragments for all iterations (once)
  k_wprep_l1<<<(NI_*9*2*64  + 255)/256, 256, 0, stream>>>(pw1, WF1H, WF1L);
  k_wprep_l2<<<(NI_*27*2*64 + 255)/256, 256, 0, stream>>>(pw2, WF2H, WF2L);
  k_wprep_l3<<<(NI_*27*64   + 255)/256, 256, 0, stream>>>(pw3, WF3H, WF3L);

  for (int k = 0; k < NI_; k++){
    k_permute_f<<<256, 256, 0, stream>>>(primal, f_flat);
    if (use_bf16) k_evalop1_bf <<<dim3(JD_, B_), 256, 0, stream>>>(AnB, f_flat, ev1);
    else          k_evalop1_f32<<<dim3(JD_, B_), 256, 0, stream>>>(An,  f_flat, ev1);

    k_conv2d<7, 32, true,  false><<<192, 256, 0, stream>>>(dual, ev1, g,
        dw1 + k*2016, db1 + k*32, da1 + k, h2a);
    k_conv2d<32, 32, true, false><<<192, 256, 0, stream>>>(h2a, nullptr, nullptr,
        dw2 + k*9216, db2 + k*32, da2 + k, h2b);
    k_conv2d<32, 5, false, true><<<30, 256, 0, stream>>>(h2b, nullptr, nullptr,
        dw3 + k*1440, db3 + k*5, nullptr, dual);

    if (use_bf16) k_back_bf <<<dim3(V_/32, B_), 256, 0, stream>>>(AB, dual, ev2);
    else          k_back_f32<<<dim3(V_/32, B_), 256, 0, stream>>>(A,  dual, ev2);

    k_prep_l1<<<256, 256, 0, stream>>>(primal, ev2, L1H, L1L);
    k_c3l1<<<512, 256, 0, stream>>>(L1H, L1L, WF1H + (size_t)k*9*2*512, WF1L + (size_t)k*9*2*512,
                                    pb1 + k*32, pa1 + k, H3AH, H3AL);
    k_c3l2<<<512, 256, 0, stream>>>(H3AH, H3AL, WF2H + (size_t)k*27*2*512, WF2L + (size_t)k*27*2*512,
                                    pb2 + k*32, pa2 + k, H3BH, H3BL);
    k_c3l3<<<512, 256, 0, stream>>>(H3BH, H3BL, WF3H + (size_t)k*27*512, WF3L + (size_t)k*27*512,
                                    pb3 + k*5, primal);
  }

  k_output<<<256, 256, 0, stream>>>(primal, (float*)d_out);
}